// Round 13
// baseline (1164.190 us; speedup 1.0000x reference)
//
#include <hip/hip_runtime.h>
#include <hip/hip_bf16.h>

#define TTOK 4096   // B*S tokens
#define DIM  2048   // hidden dim
#define FF   4096   // expert ffn dim
#define NE   8      // experts
#define TROWS 8192  // TTOK * top_k routed rows

#define BM 256
#define BK 32       // K-tile (halved -> 64 KiB LDS -> 2 blocks/CU)
// 8 waves: 2 in M x 4 in N

typedef __attribute__((ext_vector_type(4))) float  f32x4;
typedef __attribute__((ext_vector_type(8))) short  s16x8;
typedef __attribute__((ext_vector_type(8))) unsigned short u16x8;

__device__ __forceinline__ unsigned short f2bf(float f) {
  union { __hip_bfloat16 h; unsigned short u; } cv;
  cv.h = __float2bfloat16(f);
  return cv.u;
}

// async global->LDS, 16B per lane; dest = wave-uniform base, HW adds lane*16.
__device__ __forceinline__ void gl_lds16(const void* g, void* s) {
  __builtin_amdgcn_global_load_lds(
      (__attribute__((address_space(1))) void*)(g),
      (__attribute__((address_space(3))) void*)(s), 16, 0, 0);
}

#define VMW(NN) asm volatile("s_waitcnt vmcnt(" #NN ")" ::: "memory")

// mid-phase sync: pin reads/stages before barrier, MFMA after lgkmcnt(0)
#define MIDSYNC do { \
    __builtin_amdgcn_sched_barrier(0); \
    __builtin_amdgcn_s_barrier(); \
    asm volatile("s_waitcnt lgkmcnt(0)" ::: "memory"); \
    __builtin_amdgcn_sched_barrier(0); \
  } while (0)
#define ENDB do { \
    __builtin_amdgcn_sched_barrier(0); \
    __builtin_amdgcn_s_barrier(); \
  } while (0)

// ---------------- f32 -> bf16 bulk convert (weights) ------------------------
__global__ __launch_bounds__(256) void cvt_kernel(const float* __restrict__ s,
                                                  unsigned short* __restrict__ d, int n8) {
  int i = blockIdx.x * 256 + threadIdx.x;
  if (i >= n8) return;
  f32x4 v0 = *(const f32x4*)(s + (size_t)i * 8);
  f32x4 v1 = *(const f32x4*)(s + (size_t)i * 8 + 4);
  u16x8 o;
#pragma unroll
  for (int j = 0; j < 4; ++j) { o[j] = f2bf(v0[j]); o[j + 4] = f2bf(v1[j]); }
  *(u16x8*)(d + (size_t)i * 8) = o;
}

// ---------------- router (fused: also emits xb = bf16(x)) -------------------
__global__ __launch_bounds__(256) void router_kernel(
    const float* __restrict__ x, const float* __restrict__ gate_w,
    unsigned short* __restrict__ xb,
    int* __restrict__ tope, float* __restrict__ topw, int* __restrict__ counts) {
  const int t = blockIdx.x;
  const int tid = threadIdx.x;
  const float* xr = x + (size_t)t * DIM;
  f32x4 v0 = *(const f32x4*)(xr + tid * 8);
  f32x4 v1 = *(const f32x4*)(xr + tid * 8 + 4);
  {
    u16x8 o;
#pragma unroll
    for (int j = 0; j < 4; ++j) { o[j] = f2bf(v0[j]); o[j + 4] = f2bf(v1[j]); }
    *(u16x8*)(xb + (size_t)t * DIM + tid * 8) = o;
  }
  float p[NE];
#pragma unroll
  for (int e = 0; e < NE; ++e) {
    const float* g = gate_w + e * DIM + tid * 8;
    f32x4 g0 = *(const f32x4*)g;
    f32x4 g1 = *(const f32x4*)(g + 4);
    float s = 0.f;
#pragma unroll
    for (int j = 0; j < 4; ++j) s += v0[j] * g0[j] + v1[j] * g1[j];
    p[e] = s;
  }
#pragma unroll
  for (int off = 32; off > 0; off >>= 1) {
#pragma unroll
    for (int e = 0; e < NE; ++e) p[e] += __shfl_down(p[e], off);
  }
  __shared__ float red[4][NE];
  const int wid = tid >> 6, lane = tid & 63;
  if (lane == 0) {
#pragma unroll
    for (int e = 0; e < NE; ++e) red[wid][e] = p[e];
  }
  __syncthreads();
  if (tid == 0) {
    float l[NE];
#pragma unroll
    for (int e = 0; e < NE; ++e) l[e] = red[0][e] + red[1][e] + red[2][e] + red[3][e];
    float mx = l[0];
#pragma unroll
    for (int e = 1; e < NE; ++e) mx = fmaxf(mx, l[e]);
    float pr[NE]; float sum = 0.f;
#pragma unroll
    for (int e = 0; e < NE; ++e) { pr[e] = __expf(l[e] - mx); sum += pr[e]; }
    float inv = 1.f / sum;
#pragma unroll
    for (int e = 0; e < NE; ++e) pr[e] *= inv;
    int i0 = 0; float p0 = pr[0];
#pragma unroll
    for (int e = 1; e < NE; ++e) if (pr[e] > p0) { p0 = pr[e]; i0 = e; }
    int i1 = -1; float p1 = -1.f;
#pragma unroll
    for (int e = 0; e < NE; ++e) if (e != i0 && pr[e] > p1) { p1 = pr[e]; i1 = e; }
    float wsum = p0 + p1;
    tope[t * 2 + 0] = i0; topw[t * 2 + 0] = p0 / wsum;
    tope[t * 2 + 1] = i1; topw[t * 2 + 1] = p1 / wsum;
    atomicAdd(&counts[i0], 1);
    atomicAdd(&counts[i1], 1);
  }
}

__global__ void prefix_kernel(const int* __restrict__ counts, int* __restrict__ basep) {
  if (threadIdx.x == 0 && blockIdx.x == 0) {
    int acc = 0;
    for (int e = 0; e < NE; ++e) { basep[e] = acc; acc += counts[e]; }
  }
}

__global__ void fill_kernel(const int* __restrict__ tope, const float* __restrict__ topw,
                            const int* __restrict__ basep, int* __restrict__ fillp,
                            int* __restrict__ rowtok, float* __restrict__ roww,
                            int* __restrict__ rowof) {
  int t = blockIdx.x * blockDim.x + threadIdx.x;
  if (t >= TTOK) return;
#pragma unroll
  for (int s = 0; s < 2; ++s) {
    int e = tope[t * 2 + s];
    int r = basep[e] + atomicAdd(&fillp[e], 1);
    rowtok[r] = t;
    roww[r] = topw[t * 2 + s];
    rowof[t * 2 + s] = r;
  }
}

// ====== fused GEMM1: H = silu(Xe@w1^T) * (Xe@w3^T), 256x128, BK=32 ==========
// 64 KiB LDS -> 2 blocks/CU. Round-8 ledger shape: A(t+1)->opposite buf at
// p1/p2; B1(t+2)/B3(t+2)->current buf at p3/p4 (after their last reads).
// In-flight never exceeds 6; gate VMW(2) at p4/p8 drains exactly next tile.
__global__ __launch_bounds__(512) void gemm1f(
    const unsigned short* __restrict__ xb, const unsigned short* __restrict__ w1b,
    const unsigned short* __restrict__ w3b, const int* __restrict__ rowtok,
    const int* __restrict__ counts, const int* __restrict__ basep,
    unsigned short* __restrict__ H) {
  // ---- T1 bijective XCD chunk remap (x-fastest within chunk) ----
  constexpr int GX = FF / 128;     // 32
  constexpr int GY = TTOK / BM;    // 16
  constexpr int Q  = GX * GY;      // nwg/8
  int lin = (blockIdx.z * GY + blockIdx.y) * GX + blockIdx.x;
  int wg = (lin & 7) * Q + (lin >> 3);
  const int e   = wg / (GX * GY);
  const int rem = wg % (GX * GY);
  const int m0  = (rem / GX) * BM;
  const int n0  = (rem % GX) * 128;

  const int cnt = counts[e];
  if (m0 >= cnt) return;
  const int base_e = basep[e];

  __shared__ unsigned short As[2][BM * BK];    // 2 x 16 KiB
  __shared__ unsigned short B1s[2][128 * BK];  // 2 x 8 KiB
  __shared__ unsigned short B3s[2][128 * BK];  // 2 x 8 KiB  (total 64 KiB)

  const int tid = threadIdx.x;
  const int lane = tid & 63;
  const int w = tid >> 6;          // 0..7
  const int wm = w >> 2;           // 0..1  (M half)
  const int wn = w & 3;            // 0..3  (N quarter of 128)

  // staging: one gl_lds issue = 1024B = 16 rows x 64B; lane covers row lsub,
  // 16B slot lslot. Source pre-swizzled so linear LDS + swizzled read match.
  const int lsub  = lane >> 2;     // 0..15 row within issue
  const int lslot = lane & 3;      // 0..3 slot within 64B row
  const int swz_e = 8 * (lslot ^ ((lsub >> 1) & 3));

  const unsigned short* pA[2];
#pragma unroll
  for (int s = 0; s < 2; ++s) {
    int rl = w * 32 + s * 16 + lsub;          // A rows per wave: w*32..+31
    int ga = m0 + rl; if (ga > cnt - 1) ga = cnt - 1;
    int tok = rowtok[base_e + ga];
    pA[s] = xb + (size_t)tok * DIM + swz_e;
  }
  const unsigned short* pB1 = w1b + ((size_t)e * FF + n0 + w * 16 + lsub) * DIM + swz_e;
  const unsigned short* pB3 = w3b + ((size_t)e * FF + n0 + w * 16 + lsub) * DIM + swz_e;

  const int frow = lane & 15;
  const int klane = lane >> 4;     // 0..3
  const int kse = 8 * (klane ^ ((frow >> 1) & 3));   // swizzled read col

  f32x4 acc1[8][2], acc3[8][2];
#pragma unroll
  for (int mf = 0; mf < 8; ++mf)
#pragma unroll
    for (int nf = 0; nf < 2; ++nf) { acc1[mf][nf] = (f32x4)0.f; acc3[mf][nf] = (f32x4)0.f; }

#define ST_A(BUF, ISS, T) \
    gl_lds16(pA[ISS] + (size_t)(T) * BK, &As[BUF][(w * 32 + (ISS) * 16) * BK])
#define ST_B1(BUF, T) \
    gl_lds16(pB1 + (size_t)(T) * BK, &B1s[BUF][(w * 16) * BK])
#define ST_B3(BUF, T) \
    gl_lds16(pB3 + (size_t)(T) * BK, &B3s[BUF][(w * 16) * BK])

#define RD_A(MH, BUF) do { \
    _Pragma("unroll") \
    for (int ii = 0; ii < 4; ++ii) \
      a[ii] = *(const s16x8*)&As[BUF][(wm * 128 + (MH) * 64 + ii * 16 + frow) * BK + kse]; \
  } while (0)
#define RD_BX(DST, ARR, BUF) do { \
    _Pragma("unroll") \
    for (int j = 0; j < 2; ++j) \
      DST[j] = *(const s16x8*)&ARR[BUF][(wn * 32 + j * 16 + frow) * BK + kse]; \
  } while (0)

#define MMX(ACC, MH, BB) do { \
    __builtin_amdgcn_s_setprio(1); \
    _Pragma("unroll") \
    for (int ii = 0; ii < 4; ++ii) \
      _Pragma("unroll") \
      for (int j = 0; j < 2; ++j) \
        ACC[(MH) * 4 + ii][j] = __builtin_amdgcn_mfma_f32_16x16x32_bf16( \
            a[ii], BB[j], ACC[(MH) * 4 + ii][j], 0, 0, 0); \
    __builtin_amdgcn_s_setprio(0); \
  } while (0)

  const int NT = DIM / BK;   // 64

  // prologue: A(0)x2,B1(0),B3(0) -> buf0; B1(1),B3(1) -> buf1; keep last 2
  ST_A(0, 0, 0); ST_A(0, 1, 0);
  ST_B1(0, 0); ST_B3(0, 0);
  ST_B1(1, 1); ST_B3(1, 1);
  VMW(2);
  __builtin_amdgcn_s_barrier();

  s16x8 a[4], bl[2], bh[2];

  for (int t = 0; t < NT; t += 2) {
    const bool full = (t + 2 < NT);

    // ===== tile t (buf0) =====
    RD_A(0, 0); RD_BX(bl, B1s, 0);
    ST_A(1, 0, t + 1);
    MIDSYNC; MMX(acc1, 0, bl); ENDB;

    RD_BX(bh, B3s, 0);
    ST_A(1, 1, t + 1);
    MIDSYNC; MMX(acc3, 0, bh); ENDB;

    RD_A(1, 0);
    if (full) ST_B1(0, t + 2);
    MIDSYNC; MMX(acc3, 1, bh); ENDB;

    if (full) ST_B3(0, t + 2);
    MIDSYNC; MMX(acc1, 1, bl);
    if (full) { VMW(2); } else { VMW(0); }
    ENDB;

    // ===== tile t+1 (buf1) =====
    RD_A(0, 1); RD_BX(bl, B1s, 1);
    if (full) ST_A(0, 0, t + 2);
    MIDSYNC; MMX(acc1, 0, bl); ENDB;

    RD_BX(bh, B3s, 1);
    if (full) ST_A(0, 1, t + 2);
    MIDSYNC; MMX(acc3, 0, bh); ENDB;

    RD_A(1, 1);
    if (full) ST_B1(1, t + 3);
    MIDSYNC; MMX(acc3, 1, bh); ENDB;

    if (full) ST_B3(1, t + 3);
    MIDSYNC; MMX(acc1, 1, bl);
    if (full) { VMW(2); }
    ENDB;
  }
#undef ST_A
#undef ST_B1
#undef ST_B3
#undef RD_A
#undef RD_BX
#undef MMX

  // ---- epilogue: SwiGLU fused; row = wm*128 + (mf>>2)*64 + (mf&3)*16 ----
#pragma unroll
  for (int mf = 0; mf < 8; ++mf) {
#pragma unroll
    for (int nf = 0; nf < 2; ++nf) {
      int col = n0 + wn * 32 + nf * 16 + frow;
      f32x4 c1 = acc1[mf][nf], c3 = acc3[mf][nf];
#pragma unroll
      for (int j = 0; j < 4; ++j) {
        int rl = wm * 128 + (mf >> 2) * 64 + (mf & 3) * 16 + klane * 4 + j;
        int grow = m0 + rl;
        if (grow < cnt) {
          float s = c1[j];
          float hval = (s / (1.f + __expf(-s))) * c3[j];
          H[(size_t)(base_e + grow) * FF + col] = f2bf(hval);
        }
      }
    }
  }
}

// ====== GEMM2: R = roww * (H @ w2^T), 256x256, BK=32, 2 blocks/CU ===========
template <int K, int N>
__global__ __launch_bounds__(512) void gemm8(
    const unsigned short* __restrict__ Asrc, const unsigned short* __restrict__ Bw,
    const float* __restrict__ roww, const int* __restrict__ counts,
    const int* __restrict__ basep, float* __restrict__ Out) {
  // ---- T1 bijective XCD chunk remap ----
  constexpr int GX = N / BM;       // 8
  constexpr int GY = TTOK / BM;    // 16
  constexpr int Q  = GX * GY;
  int lin = (blockIdx.z * GY + blockIdx.y) * GX + blockIdx.x;
  int wg = (lin & 7) * Q + (lin >> 3);
  const int e   = wg / (GX * GY);
  const int rem = wg % (GX * GY);
  const int m0  = (rem / GX) * BM;
  const int n0  = (rem % GX) * BM;

  const int cnt = counts[e];
  if (m0 >= cnt) return;
  const int base_e = basep[e];

  __shared__ unsigned short As[2][BM * BK];   // 2 x 16 KiB
  __shared__ unsigned short Bs[2][BM * BK];   // 2 x 16 KiB (total 64 KiB)

  const int tid = threadIdx.x;
  const int lane = tid & 63;
  const int w = tid >> 6;
  const int wm = w >> 2;
  const int wn = w & 3;

  const int lsub  = lane >> 2;
  const int lslot = lane & 3;
  const int swz_e = 8 * (lslot ^ ((lsub >> 1) & 3));

  const unsigned short* pA[2];
  const unsigned short* pB[2];
#pragma unroll
  for (int s = 0; s < 2; ++s) {
    int rl = w * 32 + s * 16 + lsub;
    int ga = m0 + rl; if (ga > cnt - 1) ga = cnt - 1;
    pA[s] = Asrc + (size_t)(base_e + ga) * K + swz_e;
    pB[s] = Bw + ((size_t)e * N + n0 + rl) * K + swz_e;
  }

  const int frow = lane & 15;
  const int klane = lane >> 4;
  const int kse = 8 * (klane ^ ((frow >> 1) & 3));

  f32x4 acc[8][4];
#pragma unroll
  for (int mf = 0; mf < 8; ++mf)
#pragma unroll
    for (int nf = 0; nf < 4; ++nf) acc[mf][nf] = (f32x4)0.f;

#define ST_A(BUF, ISS, T) \
    gl_lds16(pA[ISS] + (size_t)(T) * BK, &As[BUF][(w * 32 + (ISS) * 16) * BK])
#define ST_B(BUF, ISS, T) \
    gl_lds16(pB[ISS] + (size_t)(T) * BK, &Bs[BUF][(w * 32 + (ISS) * 16) * BK])

#define RD_A(MH, BUF) do { \
    _Pragma("unroll") \
    for (int ii = 0; ii < 4; ++ii) \
      a[ii] = *(const s16x8*)&As[BUF][(wm * 128 + (MH) * 64 + ii * 16 + frow) * BK + kse]; \
  } while (0)
#define RD_B(DST, NH, BUF) do { \
    _Pragma("unroll") \
    for (int j = 0; j < 2; ++j) \
      DST[j] = *(const s16x8*)&Bs[BUF][(wn * 64 + (NH) * 32 + j * 16 + frow) * BK + kse]; \
  } while (0)

#define MM(MH, NH, BB) do { \
    __builtin_amdgcn_s_setprio(1); \
    _Pragma("unroll") \
    for (int ii = 0; ii < 4; ++ii) \
      _Pragma("unroll") \
      for (int j = 0; j < 2; ++j) \
        acc[(MH) * 4 + ii][(NH) * 2 + j] = __builtin_amdgcn_mfma_f32_16x16x32_bf16( \
            a[ii], BB[j], acc[(MH) * 4 + ii][(NH) * 2 + j], 0, 0, 0); \
    __builtin_amdgcn_s_setprio(0); \
  } while (0)

  const int NT = K / BK;   // 128

  // prologue: A(0)x2, B(0)x2 -> buf0; B(1)x2 -> buf1; keep last 2
  ST_A(0, 0, 0); ST_A(0, 1, 0);
  ST_B(0, 0, 0); ST_B(0, 1, 0);
  ST_B(1, 0, 1); ST_B(1, 1, 1);
  VMW(2);
  __builtin_amdgcn_s_barrier();

  s16x8 a[4], bl[2], bh[2];

  for (int t = 0; t < NT; t += 2) {
    const bool full = (t + 2 < NT);

    // ===== tile t (buf0) =====
    RD_A(0, 0); RD_B(bl, 0, 0);
    ST_A(1, 0, t + 1);
    MIDSYNC; MM(0, 0, bl); ENDB;

    RD_B(bh, 1, 0);
    ST_A(1, 1, t + 1);
    MIDSYNC; MM(0, 1, bh); ENDB;

    RD_A(1, 0);
    if (full) ST_B(0, 0, t + 2);
    MIDSYNC; MM(1, 1, bh); ENDB;

    if (full) ST_B(0, 1, t + 2);
    MIDSYNC; MM(1, 0, bl);
    if (full) { VMW(2); } else { VMW(0); }
    ENDB;

    // ===== tile t+1 (buf1) =====
    RD_A(0, 1); RD_B(bl, 0, 1);
    if (full) ST_A(0, 0, t + 2);
    MIDSYNC; MM(0, 0, bl); ENDB;

    RD_B(bh, 1, 1);
    if (full) ST_A(0, 1, t + 2);
    MIDSYNC; MM(0, 1, bh); ENDB;

    RD_A(1, 1);
    if (full) ST_B(1, 0, t + 3);
    MIDSYNC; MM(1, 1, bh); ENDB;

    if (full) ST_B(1, 1, t + 3);
    MIDSYNC; MM(1, 0, bl);
    if (full) { VMW(2); }
    ENDB;
  }
#undef ST_A
#undef ST_B
#undef RD_A
#undef RD_B
#undef MM

#pragma unroll
  for (int mf = 0; mf < 8; ++mf) {
#pragma unroll
    for (int nf = 0; nf < 4; ++nf) {
      int col = n0 + wn * 64 + nf * 16 + frow;
#pragma unroll
      for (int j = 0; j < 4; ++j) {
        int rl = wm * 128 + (mf >> 2) * 64 + (mf & 3) * 16 + klane * 4 + j;
        int grow = m0 + rl;
        if (grow < cnt) {
          float wv = roww[base_e + grow];
          Out[(size_t)(base_e + grow) * N + col] = acc[mf][nf][j] * wv;
        }
      }
    }
  }
}

// y[t,:] = R[row0(t),:] + R[row1(t),:]
__global__ __launch_bounds__(256) void combine_kernel(const float* __restrict__ R,
                                                      const int* __restrict__ rowof,
                                                      float* __restrict__ y) {
  int idx = blockIdx.x * 256 + threadIdx.x;
  int t = idx >> 9;                           // D/4 = 512
  int d4 = idx & 511;
  int r0 = rowof[t * 2], r1 = rowof[t * 2 + 1];
  f32x4 a = *(const f32x4*)(R + (size_t)r0 * DIM + d4 * 4);
  f32x4 b = *(const f32x4*)(R + (size_t)r1 * DIM + d4 * 4);
  *(f32x4*)(y + (size_t)t * DIM + d4 * 4) = a + b;
}

extern "C" void kernel_launch(void* const* d_in, const int* in_sizes, int n_in,
                              void* d_out, int out_size, void* d_ws, size_t ws_size,
                              hipStream_t stream) {
  const float* x      = (const float*)d_in[0];
  const float* gate_w = (const float*)d_in[1];
  const float* w1     = (const float*)d_in[2];
  const float* w2     = (const float*)d_in[3];
  const float* w3     = (const float*)d_in[4];
  float* y = (float*)d_out;

  char* ws = (char*)d_ws;
  const size_t MB = 1ull << 20;
  int*   tope   = (int*)(ws);
  float* topw   = (float*)(ws + (32 << 10));
  int*   rowtok = (int*)(ws + (64 << 10));
  float* roww   = (float*)(ws + (96 << 10));
  int*   rowof  = (int*)(ws + (128 << 10));
  int*   counts = (int*)(ws + (160 << 10));
  int*   basep  = counts + 32;
  int*   fillp  = counts + 64;

  unsigned short* xb  = (unsigned short*)(ws + 1 * MB);    // 16 MB
  unsigned short* H1  = (unsigned short*)(ws + 17 * MB);   // 64 MB (fused H)
  float*          R   = (float*)(ws + 81 * MB);            // 64 MB
  unsigned short* w1b = (unsigned short*)(ws + 145 * MB);  // 128 MB
  unsigned short* w3b = (unsigned short*)(ws + 273 * MB);  // 128 MB
  unsigned short* w2b = (unsigned short*)(ws + 401 * MB);  // 128 MB (end 529)

  hipMemsetAsync(counts, 0, 512, stream);
  router_kernel<<<TTOK, 256, 0, stream>>>(x, gate_w, xb, tope, topw, counts);
  prefix_kernel<<<1, 64, 0, stream>>>(counts, basep);
  fill_kernel<<<TTOK / 256, 256, 0, stream>>>(tope, topw, basep, fillp, rowtok, roww, rowof);

  const int nw8 = NE * FF * DIM / 8;
  cvt_kernel<<<nw8 / 256, 256, 0, stream>>>(w1, w1b, nw8);
  cvt_kernel<<<nw8 / 256, 256, 0, stream>>>(w3, w3b, nw8);
  cvt_kernel<<<nw8 / 256, 256, 0, stream>>>(w2, w2b, nw8);

  // fused: H = silu(Xe@w1^T) * (Xe@w3^T)
  gemm1f<<<dim3(FF / 128, TTOK / BM, NE), 512, 0, stream>>>(
      xb, w1b, w3b, rowtok, counts, basep, H1);
  // R = roww * (H @ w2^T)
  gemm8<FF, DIM><<<dim3(DIM / BM, TTOK / BM, NE), 512, 0, stream>>>(
      H1, w2b, roww, counts, basep, R);
  combine_kernel<<<TTOK * DIM / 4 / 256, 256, 0, stream>>>(R, rowof, y);
}

// Round 14
// 966.143 us; speedup vs baseline: 1.2050x; 1.2050x over previous
//
#include <hip/hip_runtime.h>
#include <hip/hip_bf16.h>

#define TTOK 4096   // B*S tokens
#define DIM  2048   // hidden dim
#define FF   4096   // expert ffn dim
#define NE   8      // experts
#define TROWS 8192  // TTOK * top_k routed rows

#define BM 256
#define BK 64       // K-tile
// 8 waves: 2 in M x 4 in N

typedef __attribute__((ext_vector_type(4))) float  f32x4;
typedef __attribute__((ext_vector_type(8))) short  s16x8;
typedef __attribute__((ext_vector_type(8))) unsigned short u16x8;

__device__ __forceinline__ unsigned short f2bf(float f) {
  union { __hip_bfloat16 h; unsigned short u; } cv;
  cv.h = __float2bfloat16(f);
  return cv.u;
}

// async global->LDS, 16B per lane; dest = wave-uniform base, HW adds lane*16.
__device__ __forceinline__ void gl_lds16(const void* g, void* s) {
  __builtin_amdgcn_global_load_lds(
      (__attribute__((address_space(1))) void*)(g),
      (__attribute__((address_space(3))) void*)(s), 16, 0, 0);
}

#define VMW(NN) asm volatile("s_waitcnt vmcnt(" #NN ")" ::: "memory")

// mid-phase sync: pin reads/stages before barrier, MFMA after lgkmcnt(0)
#define MIDSYNC do { \
    __builtin_amdgcn_sched_barrier(0); \
    __builtin_amdgcn_s_barrier(); \
    asm volatile("s_waitcnt lgkmcnt(0)" ::: "memory"); \
    __builtin_amdgcn_sched_barrier(0); \
  } while (0)
#define ENDB do { \
    __builtin_amdgcn_sched_barrier(0); \
    __builtin_amdgcn_s_barrier(); \
  } while (0)

// ---------------- f32 -> bf16 convert, all 3 weight tensors in one grid -----
// n8 per tensor = NE*FF*DIM/8 = 2^23 exactly -> select via shift/mask.
__global__ __launch_bounds__(256) void cvt3_kernel(
    const float* __restrict__ s1, const float* __restrict__ s2,
    const float* __restrict__ s3, unsigned short* __restrict__ d1,
    unsigned short* __restrict__ d2, unsigned short* __restrict__ d3) {
  int i = blockIdx.x * 256 + threadIdx.x;
  int which = i >> 23;
  size_t off = (size_t)(i & ((1 << 23) - 1)) * 8;
  const float* s = (which == 0) ? s1 : (which == 1) ? s2 : s3;
  unsigned short* d = (which == 0) ? d1 : (which == 1) ? d2 : d3;
  f32x4 v0 = *(const f32x4*)(s + off);
  f32x4 v1 = *(const f32x4*)(s + off + 4);
  u16x8 o;
#pragma unroll
  for (int j = 0; j < 4; ++j) { o[j] = f2bf(v0[j]); o[j + 4] = f2bf(v1[j]); }
  *(u16x8*)(d + off) = o;
}

// ---------------- router (fused: also emits xb = bf16(x)) -------------------
__global__ __launch_bounds__(256) void router_kernel(
    const float* __restrict__ x, const float* __restrict__ gate_w,
    unsigned short* __restrict__ xb,
    int* __restrict__ tope, float* __restrict__ topw, int* __restrict__ counts) {
  const int t = blockIdx.x;
  const int tid = threadIdx.x;
  const float* xr = x + (size_t)t * DIM;
  f32x4 v0 = *(const f32x4*)(xr + tid * 8);
  f32x4 v1 = *(const f32x4*)(xr + tid * 8 + 4);
  {
    u16x8 o;
#pragma unroll
    for (int j = 0; j < 4; ++j) { o[j] = f2bf(v0[j]); o[j + 4] = f2bf(v1[j]); }
    *(u16x8*)(xb + (size_t)t * DIM + tid * 8) = o;
  }
  float p[NE];
#pragma unroll
  for (int e = 0; e < NE; ++e) {
    const float* g = gate_w + e * DIM + tid * 8;
    f32x4 g0 = *(const f32x4*)g;
    f32x4 g1 = *(const f32x4*)(g + 4);
    float s = 0.f;
#pragma unroll
    for (int j = 0; j < 4; ++j) s += v0[j] * g0[j] + v1[j] * g1[j];
    p[e] = s;
  }
#pragma unroll
  for (int off = 32; off > 0; off >>= 1) {
#pragma unroll
    for (int e = 0; e < NE; ++e) p[e] += __shfl_down(p[e], off);
  }
  __shared__ float red[4][NE];
  const int wid = tid >> 6, lane = tid & 63;
  if (lane == 0) {
#pragma unroll
    for (int e = 0; e < NE; ++e) red[wid][e] = p[e];
  }
  __syncthreads();
  if (tid == 0) {
    float l[NE];
#pragma unroll
    for (int e = 0; e < NE; ++e) l[e] = red[0][e] + red[1][e] + red[2][e] + red[3][e];
    float mx = l[0];
#pragma unroll
    for (int e = 1; e < NE; ++e) mx = fmaxf(mx, l[e]);
    float pr[NE]; float sum = 0.f;
#pragma unroll
    for (int e = 0; e < NE; ++e) { pr[e] = __expf(l[e] - mx); sum += pr[e]; }
    float inv = 1.f / sum;
#pragma unroll
    for (int e = 0; e < NE; ++e) pr[e] *= inv;
    int i0 = 0; float p0 = pr[0];
#pragma unroll
    for (int e = 1; e < NE; ++e) if (pr[e] > p0) { p0 = pr[e]; i0 = e; }
    int i1 = -1; float p1 = -1.f;
#pragma unroll
    for (int e = 0; e < NE; ++e) if (e != i0 && pr[e] > p1) { p1 = pr[e]; i1 = e; }
    float wsum = p0 + p1;
    tope[t * 2 + 0] = i0; topw[t * 2 + 0] = p0 / wsum;
    tope[t * 2 + 1] = i1; topw[t * 2 + 1] = p1 / wsum;
    atomicAdd(&counts[i0], 1);
    atomicAdd(&counts[i1], 1);
  }
}

__global__ void prefix_kernel(const int* __restrict__ counts, int* __restrict__ basep) {
  if (threadIdx.x == 0 && blockIdx.x == 0) {
    int acc = 0;
    for (int e = 0; e < NE; ++e) { basep[e] = acc; acc += counts[e]; }
  }
}

__global__ void fill_kernel(const int* __restrict__ tope, const float* __restrict__ topw,
                            const int* __restrict__ basep, int* __restrict__ fillp,
                            int* __restrict__ rowtok, float* __restrict__ roww,
                            int* __restrict__ rowof) {
  int t = blockIdx.x * blockDim.x + threadIdx.x;
  if (t >= TTOK) return;
#pragma unroll
  for (int s = 0; s < 2; ++s) {
    int e = tope[t * 2 + s];
    int r = basep[e] + atomicAdd(&fillp[e], 1);
    rowtok[r] = t;
    roww[r] = topw[t * 2 + s];
    rowof[t * 2 + s] = r;
  }
}

// ====== fused GEMM1: H = silu(Xe@w1^T) * (Xe@w3^T), 256x128, 8-phase ========
// ROUND-6-PROVEN LEDGER: A(t+1) -> OPPOSITE buffer at p1/p2 (gated by VMW(4)
// at p4); B1(t+2)/B3(t+2) -> same buffer at p3/p4, after their phase-reads.
__global__ __launch_bounds__(512, 1) void gemm1f(
    const unsigned short* __restrict__ xb, const unsigned short* __restrict__ w1b,
    const unsigned short* __restrict__ w3b, const int* __restrict__ rowtok,
    const int* __restrict__ counts, const int* __restrict__ basep,
    unsigned short* __restrict__ H) {
  // ---- T1 bijective XCD chunk remap (x-fastest within chunk) ----
  constexpr int GX = FF / 128;     // 32
  constexpr int GY = TTOK / BM;    // 16
  constexpr int Q  = GX * GY;      // nwg/8
  int lin = (blockIdx.z * GY + blockIdx.y) * GX + blockIdx.x;
  int wg = (lin & 7) * Q + (lin >> 3);
  const int e   = wg / (GX * GY);
  const int rem = wg % (GX * GY);
  const int m0  = (rem / GX) * BM;
  const int n0  = (rem % GX) * 128;

  const int cnt = counts[e];
  if (m0 >= cnt) return;
  const int base_e = basep[e];

  __shared__ unsigned short As[2][BM * BK];    // 2 x 32 KiB
  __shared__ unsigned short B1s[2][128 * BK];  // 2 x 16 KiB
  __shared__ unsigned short B3s[2][128 * BK];  // 2 x 16 KiB

  const int tid = threadIdx.x;
  const int lane = tid & 63;
  const int w = tid >> 6;          // 0..7
  const int wm = w >> 2;           // 0..1  (M half)
  const int wn = w & 3;            // 0..3  (N quarter of 128)

  const int lsub  = lane >> 3;     // row within 8-row group
  const int lslot = lane & 7;      // 16B slot within 128B row
  const int swz_e = 8 * (lslot ^ lsub);   // pre-swizzled source slot

  const unsigned short* pA[4];
  const unsigned short* pB1[2];
  const unsigned short* pB3[2];
#pragma unroll
  for (int s = 0; s < 4; ++s) {
    int rl = s * 64 + w * 8 + lsub;
    int ga = m0 + rl; if (ga > cnt - 1) ga = cnt - 1;
    int tok = rowtok[base_e + ga];
    pA[s] = xb + (size_t)tok * DIM + swz_e;
  }
#pragma unroll
  for (int s = 0; s < 2; ++s) {
    int rl = s * 64 + w * 8 + lsub;
    pB1[s] = w1b + ((size_t)e * FF + n0 + rl) * DIM + swz_e;
    pB3[s] = w3b + ((size_t)e * FF + n0 + rl) * DIM + swz_e;
  }

  const int frow = lane & 15;
  const int klane = lane >> 4;     // 0..3
  const int ks0 = (klane * 8) ^ ((frow & 7) * 8);
  const int ks1 = (32 + klane * 8) ^ ((frow & 7) * 8);

  f32x4 acc1[8][2], acc3[8][2];
#pragma unroll
  for (int mf = 0; mf < 8; ++mf)
#pragma unroll
    for (int nf = 0; nf < 2; ++nf) { acc1[mf][nf] = (f32x4)0.f; acc3[mf][nf] = (f32x4)0.f; }

#define ST_A(BUF, G0, T) do { \
    gl_lds16(pA[G0]     + (size_t)(T) * BK, &As[BUF][((G0) * 64 + w * 8) * BK]); \
    gl_lds16(pA[(G0)+1] + (size_t)(T) * BK, &As[BUF][(((G0)+1) * 64 + w * 8) * BK]); \
  } while (0)
#define ST_B1(BUF, T) do { \
    gl_lds16(pB1[0] + (size_t)(T) * BK, &B1s[BUF][(0  + w * 8) * BK]); \
    gl_lds16(pB1[1] + (size_t)(T) * BK, &B1s[BUF][(64 + w * 8) * BK]); \
  } while (0)
#define ST_B3(BUF, T) do { \
    gl_lds16(pB3[0] + (size_t)(T) * BK, &B3s[BUF][(0  + w * 8) * BK]); \
    gl_lds16(pB3[1] + (size_t)(T) * BK, &B3s[BUF][(64 + w * 8) * BK]); \
  } while (0)

#define RD_A(MH, BUF) do { \
    _Pragma("unroll") \
    for (int ii = 0; ii < 4; ++ii) { \
      a[ii][0] = *(const s16x8*)&As[BUF][(wm * 128 + (MH) * 64 + ii * 16 + frow) * BK + ks0]; \
      a[ii][1] = *(const s16x8*)&As[BUF][(wm * 128 + (MH) * 64 + ii * 16 + frow) * BK + ks1]; \
    } } while (0)
#define RD_BX(DST, ARR, BUF) do { \
    _Pragma("unroll") \
    for (int j = 0; j < 2; ++j) { \
      DST[j][0] = *(const s16x8*)&ARR[BUF][(wn * 32 + j * 16 + frow) * BK + ks0]; \
      DST[j][1] = *(const s16x8*)&ARR[BUF][(wn * 32 + j * 16 + frow) * BK + ks1]; \
    } } while (0)

#define MMX(ACC, MH, BB) do { \
    __builtin_amdgcn_s_setprio(1); \
    _Pragma("unroll") \
    for (int ii = 0; ii < 4; ++ii) \
      _Pragma("unroll") \
      for (int j = 0; j < 2; ++j) { \
        ACC[(MH) * 4 + ii][j] = __builtin_amdgcn_mfma_f32_16x16x32_bf16( \
            a[ii][0], BB[j][0], ACC[(MH) * 4 + ii][j], 0, 0, 0); \
        ACC[(MH) * 4 + ii][j] = __builtin_amdgcn_mfma_f32_16x16x32_bf16( \
            a[ii][1], BB[j][1], ACC[(MH) * 4 + ii][j], 0, 0, 0); \
      } \
    __builtin_amdgcn_s_setprio(0); \
  } while (0)

  const int NT = DIM / BK;   // 32

  // ---- prologue: A(0),B1(0),B3(0) -> buf0; B1(1),B3(1) -> buf1 ----
  ST_A(0, 0, 0); ST_A(0, 2, 0);
  ST_B1(0, 0); ST_B3(0, 0);
  ST_B1(1, 1); ST_B3(1, 1);
  VMW(4);
  __builtin_amdgcn_s_barrier();

  s16x8 a[4][2], bl[2][2], bh[2][2];

  for (int t = 0; t < NT; t += 2) {
    const bool full = (t + 2 < NT);

    // ===== tile t (buf0) =====
    RD_A(0, 0); RD_BX(bl, B1s, 0);
    ST_A(1, 0, t + 1);
    MIDSYNC; MMX(acc1, 0, bl); ENDB;

    RD_BX(bh, B3s, 0);
    ST_A(1, 2, t + 1);
    MIDSYNC; MMX(acc3, 0, bh); ENDB;

    RD_A(1, 0);
    if (full) ST_B1(0, t + 2);
    MIDSYNC; MMX(acc3, 1, bh); ENDB;

    if (full) ST_B3(0, t + 2);
    MIDSYNC; MMX(acc1, 1, bl);
    if (full) { VMW(4); } else { VMW(0); }
    ENDB;

    // ===== tile t+1 (buf1) =====
    RD_A(0, 1); RD_BX(bl, B1s, 1);
    if (full) ST_A(0, 0, t + 2);
    MIDSYNC; MMX(acc1, 0, bl); ENDB;

    RD_BX(bh, B3s, 1);
    if (full) ST_A(0, 2, t + 2);
    MIDSYNC; MMX(acc3, 0, bh); ENDB;

    RD_A(1, 1);
    if (full) ST_B1(1, t + 3);
    MIDSYNC; MMX(acc3, 1, bh); ENDB;

    if (full) ST_B3(1, t + 3);
    MIDSYNC; MMX(acc1, 1, bl);
    if (full) { VMW(4); }
    ENDB;
  }
#undef ST_A
#undef ST_B1
#undef ST_B3
#undef RD_A
#undef RD_BX
#undef MMX

  // ---- epilogue: SwiGLU fused; row = wm*128 + (mf>>2)*64 + (mf&3)*16 ----
#pragma unroll
  for (int mf = 0; mf < 8; ++mf) {
#pragma unroll
    for (int nf = 0; nf < 2; ++nf) {
      int col = n0 + wn * 32 + nf * 16 + frow;
      f32x4 c1 = acc1[mf][nf], c3 = acc3[mf][nf];
#pragma unroll
      for (int j = 0; j < 4; ++j) {
        int rl = wm * 128 + (mf >> 2) * 64 + (mf & 3) * 16 + klane * 4 + j;
        int grow = m0 + rl;
        if (grow < cnt) {
          float s = c1[j];
          float hval = (s / (1.f + __expf(-s))) * c3[j];
          H[(size_t)(base_e + grow) * FF + col] = f2bf(hval);
        }
      }
    }
  }
}

// ====== GEMM2: R = roww * (H @ w2^T), 256x256, round-8 8-phase + T1 =========
template <int K, int N>
__global__ __launch_bounds__(512, 1) void gemm8(
    const unsigned short* __restrict__ Asrc, const unsigned short* __restrict__ Bw,
    const float* __restrict__ roww, const int* __restrict__ counts,
    const int* __restrict__ basep, float* __restrict__ Out) {
  // ---- T1 bijective XCD chunk remap ----
  constexpr int GX = N / BM;       // 8
  constexpr int GY = TTOK / BM;    // 16
  constexpr int Q  = GX * GY;
  int lin = (blockIdx.z * GY + blockIdx.y) * GX + blockIdx.x;
  int wg = (lin & 7) * Q + (lin >> 3);
  const int e   = wg / (GX * GY);
  const int rem = wg % (GX * GY);
  const int m0  = (rem / GX) * BM;
  const int n0  = (rem % GX) * BM;

  const int cnt = counts[e];
  if (m0 >= cnt) return;
  const int base_e = basep[e];

  __shared__ unsigned short As[2][BM * BK];
  __shared__ unsigned short Bs[2][BM * BK];

  const int tid = threadIdx.x;
  const int lane = tid & 63;
  const int w = tid >> 6;
  const int wm = w >> 2;
  const int wn = w & 3;

  const int lsub  = lane >> 3;
  const int lslot = lane & 7;
  const int swz_e = 8 * (lslot ^ lsub);

  const unsigned short* pA[4];
  const unsigned short* pB[4];
#pragma unroll
  for (int s = 0; s < 4; ++s) {
    int rl = s * 64 + w * 8 + lsub;
    int ga = m0 + rl; if (ga > cnt - 1) ga = cnt - 1;
    pA[s] = Asrc + (size_t)(base_e + ga) * K + swz_e;
    pB[s] = Bw + ((size_t)e * N + n0 + rl) * K + swz_e;
  }

  const int frow = lane & 15;
  const int klane = lane >> 4;
  const int ks0 = (klane * 8) ^ ((frow & 7) * 8);
  const int ks1 = (32 + klane * 8) ^ ((frow & 7) * 8);

  f32x4 acc[8][4];
#pragma unroll
  for (int mf = 0; mf < 8; ++mf)
#pragma unroll
    for (int nf = 0; nf < 4; ++nf) acc[mf][nf] = (f32x4)0.f;

#define ST_A(BUF, G0, T) do { \
    gl_lds16(pA[G0]     + (size_t)(T) * BK, &As[BUF][((G0) * 64 + w * 8) * BK]); \
    gl_lds16(pA[(G0)+1] + (size_t)(T) * BK, &As[BUF][(((G0)+1) * 64 + w * 8) * BK]); \
  } while (0)
#define ST_B(BUF, G0, T) do { \
    gl_lds16(pB[G0]     + (size_t)(T) * BK, &Bs[BUF][((G0) * 64 + w * 8) * BK]); \
    gl_lds16(pB[(G0)+1] + (size_t)(T) * BK, &Bs[BUF][(((G0)+1) * 64 + w * 8) * BK]); \
  } while (0)

#define RD_A(MH, BUF) do { \
    _Pragma("unroll") \
    for (int ii = 0; ii < 4; ++ii) { \
      a[ii][0] = *(const s16x8*)&As[BUF][(wm * 128 + (MH) * 64 + ii * 16 + frow) * BK + ks0]; \
      a[ii][1] = *(const s16x8*)&As[BUF][(wm * 128 + (MH) * 64 + ii * 16 + frow) * BK + ks1]; \
    } } while (0)
#define RD_B(DST, NH, BUF) do { \
    _Pragma("unroll") \
    for (int j = 0; j < 2; ++j) { \
      DST[j][0] = *(const s16x8*)&Bs[BUF][(wn * 64 + (NH) * 32 + j * 16 + frow) * BK + ks0]; \
      DST[j][1] = *(const s16x8*)&Bs[BUF][(wn * 64 + (NH) * 32 + j * 16 + frow) * BK + ks1]; \
    } } while (0)

#define MM(MH, NH, BB) do { \
    __builtin_amdgcn_s_setprio(1); \
    _Pragma("unroll") \
    for (int ii = 0; ii < 4; ++ii) \
      _Pragma("unroll") \
      for (int j = 0; j < 2; ++j) { \
        acc[(MH) * 4 + ii][(NH) * 2 + j] = __builtin_amdgcn_mfma_f32_16x16x32_bf16( \
            a[ii][0], BB[j][0], acc[(MH) * 4 + ii][(NH) * 2 + j], 0, 0, 0); \
        acc[(MH) * 4 + ii][(NH) * 2 + j] = __builtin_amdgcn_mfma_f32_16x16x32_bf16( \
            a[ii][1], BB[j][1], acc[(MH) * 4 + ii][(NH) * 2 + j], 0, 0, 0); \
      } \
    __builtin_amdgcn_s_setprio(0); \
  } while (0)

  const int NT = K / BK;

  ST_A(0, 0, 0); ST_A(0, 2, 0);
  ST_B(0, 0, 0); ST_B(0, 2, 0);
  ST_B(1, 0, 1); ST_B(1, 2, 1);
  VMW(4);
  __builtin_amdgcn_s_barrier();

  s16x8 a[4][2], bl[2][2], bh[2][2];

  for (int t = 0; t < NT; t += 2) {
    const bool full = (t + 2 < NT);

    RD_A(0, 0); RD_B(bl, 0, 0);
    ST_A(1, 0, t + 1);
    MIDSYNC; MM(0, 0, bl); ENDB;

    RD_B(bh, 1, 0);
    ST_A(1, 2, t + 1);
    MIDSYNC; MM(0, 1, bh); ENDB;

    RD_A(1, 0);
    if (full) ST_B(0, 0, t + 2);
    MIDSYNC; MM(1, 1, bh); ENDB;

    if (full) ST_B(0, 2, t + 2);
    MIDSYNC; MM(1, 0, bl);
    if (full) { VMW(4); } else { VMW(0); }
    ENDB;

    RD_A(0, 1); RD_B(bl, 0, 1);
    if (full) ST_A(0, 0, t + 2);
    MIDSYNC; MM(0, 0, bl); ENDB;

    RD_B(bh, 1, 1);
    if (full) ST_A(0, 2, t + 2);
    MIDSYNC; MM(0, 1, bh); ENDB;

    RD_A(1, 1);
    if (full) ST_B(1, 0, t + 3);
    MIDSYNC; MM(1, 1, bh); ENDB;

    if (full) ST_B(1, 2, t + 3);
    MIDSYNC; MM(1, 0, bl);
    if (full) { VMW(4); }
    ENDB;
  }
#undef ST_A
#undef ST_B
#undef RD_A
#undef RD_B
#undef MM

#pragma unroll
  for (int mf = 0; mf < 8; ++mf) {
#pragma unroll
    for (int nf = 0; nf < 4; ++nf) {
      int col = n0 + wn * 64 + nf * 16 + frow;
#pragma unroll
      for (int j = 0; j < 4; ++j) {
        int rl = wm * 128 + (mf >> 2) * 64 + (mf & 3) * 16 + klane * 4 + j;
        int grow = m0 + rl;
        if (grow < cnt) {
          float wv = roww[base_e + grow];
          Out[(size_t)(base_e + grow) * N + col] = acc[mf][nf][j] * wv;
        }
      }
    }
  }
}

// y[t,:] = R[row0(t),:] + R[row1(t),:]
__global__ __launch_bounds__(256) void combine_kernel(const float* __restrict__ R,
                                                      const int* __restrict__ rowof,
                                                      float* __restrict__ y) {
  int idx = blockIdx.x * 256 + threadIdx.x;
  int t = idx >> 9;                           // D/4 = 512
  int d4 = idx & 511;
  int r0 = rowof[t * 2], r1 = rowof[t * 2 + 1];
  f32x4 a = *(const f32x4*)(R + (size_t)r0 * DIM + d4 * 4);
  f32x4 b = *(const f32x4*)(R + (size_t)r1 * DIM + d4 * 4);
  *(f32x4*)(y + (size_t)t * DIM + d4 * 4) = a + b;
}

extern "C" void kernel_launch(void* const* d_in, const int* in_sizes, int n_in,
                              void* d_out, int out_size, void* d_ws, size_t ws_size,
                              hipStream_t stream) {
  const float* x      = (const float*)d_in[0];
  const float* gate_w = (const float*)d_in[1];
  const float* w1     = (const float*)d_in[2];
  const float* w2     = (const float*)d_in[3];
  const float* w3     = (const float*)d_in[4];
  float* y = (float*)d_out;

  char* ws = (char*)d_ws;
  const size_t MB = 1ull << 20;
  int*   tope   = (int*)(ws);
  float* topw   = (float*)(ws + (32 << 10));
  int*   rowtok = (int*)(ws + (64 << 10));
  float* roww   = (float*)(ws + (96 << 10));
  int*   rowof  = (int*)(ws + (128 << 10));
  int*   counts = (int*)(ws + (160 << 10));
  int*   basep  = counts + 32;
  int*   fillp  = counts + 64;

  unsigned short* xb  = (unsigned short*)(ws + 1 * MB);    // 16 MB
  unsigned short* H1  = (unsigned short*)(ws + 17 * MB);   // 64 MB (fused H)
  float*          R   = (float*)(ws + 81 * MB);            // 64 MB
  unsigned short* w1b = (unsigned short*)(ws + 145 * MB);  // 128 MB
  unsigned short* w3b = (unsigned short*)(ws + 273 * MB);  // 128 MB
  unsigned short* w2b = (unsigned short*)(ws + 401 * MB);  // 128 MB (end 529)

  hipMemsetAsync(counts, 0, 512, stream);
  router_kernel<<<TTOK, 256, 0, stream>>>(x, gate_w, xb, tope, topw, counts);
  prefix_kernel<<<1, 64, 0, stream>>>(counts, basep);
  fill_kernel<<<TTOK / 256, 256, 0, stream>>>(tope, topw, basep, fillp, rowtok, roww, rowof);

  // all three weight tensors in one BW-bound pass (3 * 2^23 chunks of 8)
  cvt3_kernel<<<3 * (1 << 23) / 256, 256, 0, stream>>>(w1, w3, w2, w1b, w3b, w2b);

  // fused: H = silu(Xe@w1^T) * (Xe@w3^T)
  gemm1f<<<dim3(FF / 128, TTOK / BM, NE), 512, 0, stream>>>(
      xb, w1b, w3b, rowtok, counts, basep, H1);
  // R = roww * (H @ w2^T)
  gemm8<FF, DIM><<<dim3(DIM / BM, TTOK / BM, NE), 512, 0, stream>>>(
      H1, w2b, roww, counts, basep, R);
  combine_kernel<<<TTOK * DIM / 4 / 256, 256, 0, stream>>>(R, rowof, y);
}